// Round 1
// baseline (1809.728 us; speedup 1.0000x reference)
//
#include <hip/hip_runtime.h>

// ---------------- problem constants ----------------
#define Bq   4
#define Nq   4096
#define DIMq 512
#define Hq   8
#define DHq  64
#define Mq   256
#define LGRP 16
#define BHq  (Bq*Hq)        // 32
#define INNERq (Hq*DHq)     // 512

// ---------------- workspace layout (floats) ----------------
// q,k,v: [BH][N][DH]; ql,kl: [BH][M][DH]; a2,z,xz,t1,t2: [BH][M][M]
static const size_t O_Q   = 0;                       // 8388608
static const size_t O_K   = O_Q   + (size_t)BHq*Nq*DHq;
static const size_t O_V   = O_K   + (size_t)BHq*Nq*DHq;
static const size_t O_QL  = O_V   + (size_t)BHq*Nq*DHq;
static const size_t O_KL  = O_QL  + (size_t)BHq*Mq*DHq;
static const size_t O_A2  = O_KL  + (size_t)BHq*Mq*DHq;
static const size_t O_ZA  = O_A2  + (size_t)BHq*Mq*Mq;
static const size_t O_ZB  = O_ZA  + (size_t)BHq*Mq*Mq;
static const size_t O_XZ  = O_ZB  + (size_t)BHq*Mq*Mq;
static const size_t O_T1  = O_XZ  + (size_t)BHq*Mq*Mq;
static const size_t O_T2  = O_T1  + (size_t)BHq*Mq*Mq;
static const size_t O_A3V = O_T2  + (size_t)BHq*Mq*Mq;
static const size_t O_W   = O_A3V + (size_t)BHq*Mq*DHq;
static const size_t O_OH  = O_W   + (size_t)BHq*Mq*DHq;
static const size_t O_SC  = O_OH  + (size_t)BHq*Nq*DHq;   // 2 scalars

// ---------------- helpers ----------------
__device__ __forceinline__ void fma4x4(const float4& a4, const float4& b4,
                                       float (&acc)[4][4]) {
  const float a_[4] = {a4.x, a4.y, a4.z, a4.w};
  const float b_[4] = {b4.x, b4.y, b4.z, b4.w};
#pragma unroll
  for (int i = 0; i < 4; ++i)
#pragma unroll
    for (int j = 0; j < 4; ++j) acc[i][j] = fmaf(a_[i], b_[j], acc[i][j]);
}

// ---------------- kernel 1: qkv projection, scatter to head layout ----------------
// C logical [16384 x 1536] = X[16384x512] @ Wqkv[512x1536]; q scaled by 0.125.
__global__ __launch_bounds__(256) void k_gemm_qkv(
    const float* __restrict__ X, const float* __restrict__ Wqkv,
    float* __restrict__ q, float* __restrict__ k, float* __restrict__ v) {
  const int NT = 3 * INNERq;  // 1536
  int n0 = blockIdx.x * 64, m0 = blockIdx.y * 64;
  __shared__ float As[16][64];  // [k][m]
  __shared__ float Bs[16][64];  // [k][n]
  int t = threadIdx.x, tx = t & 15, ty = t >> 4;
  float acc[4][4] = {};
  for (int k0 = 0; k0 < DIMq; k0 += 16) {
    {
      int row = t >> 2, c4 = (t & 3) * 4;
      float4 av = *(const float4*)&X[(size_t)(m0 + row) * DIMq + k0 + c4];
      As[c4 + 0][row] = av.x; As[c4 + 1][row] = av.y;
      As[c4 + 2][row] = av.z; As[c4 + 3][row] = av.w;
    }
    {
      int row = t >> 4, c4 = (t & 15) * 4;
      float4 bv = *(const float4*)&Wqkv[(size_t)(k0 + row) * NT + n0 + c4];
      *(float4*)&Bs[row][c4] = bv;
    }
    __syncthreads();
#pragma unroll
    for (int kk = 0; kk < 16; ++kk) {
      float4 a4 = *(const float4*)&As[kk][ty * 4];
      float4 b4 = *(const float4*)&Bs[kk][tx * 4];
      fma4x4(a4, b4, acc);
    }
    __syncthreads();
  }
  int c = n0 + tx * 4;
  int part = c >> 9, hd = c & 511, h = hd >> 6, d = hd & 63;
  float* dst = part == 0 ? q : (part == 1 ? k : v);
  float sc = part == 0 ? 0.125f : 1.0f;
#pragma unroll
  for (int i = 0; i < 4; ++i) {
    int row = m0 + ty * 4 + i;
    int b = row >> 12, ii = row & 4095;
    float4 val = make_float4(acc[i][0] * sc, acc[i][1] * sc,
                             acc[i][2] * sc, acc[i][3] * sc);
    *(float4*)&dst[((size_t)(b * Hq + h) * Nq + ii) * DHq + d] = val;
  }
}

// ---------------- kernel 2: landmark means ----------------
__global__ void k_landmarks(const float* __restrict__ q, const float* __restrict__ k,
                            float* __restrict__ ql, float* __restrict__ kl) {
  int bm = blockIdx.x;  // bh*M + mi
  int bh = bm >> 8, mi = bm & 255;
  int d = threadIdx.x;  // 64
  const float* qp = q + ((size_t)bh * Nq + mi * LGRP) * DHq + d;
  const float* kp = k + ((size_t)bh * Nq + mi * LGRP) * DHq + d;
  float sq = 0.f, sk = 0.f;
#pragma unroll
  for (int tt = 0; tt < LGRP; ++tt) { sq += qp[tt * DHq]; sk += kp[tt * DHq]; }
  ql[((size_t)bh * Mq + mi) * DHq + d] = sq * (1.0f / LGRP);
  kl[((size_t)bh * Mq + mi) * DHq + d] = sk * (1.0f / LGRP);
}

// ---------------- kernel 3: attn2 = softmax(q_l k_l^T) ----------------
__global__ __launch_bounds__(256) void k_attn2(const float* __restrict__ ql,
                                               const float* __restrict__ kl,
                                               float* __restrict__ a2) {
  int i = blockIdx.x, bh = blockIdx.y;
  int t = threadIdx.x;  // = j
  __shared__ float qrow[64];
  __shared__ float red[256];
  if (t < 64) qrow[t] = ql[((size_t)bh * Mq + i) * DHq + t];
  __syncthreads();
  const float* kp = kl + ((size_t)bh * Mq + t) * DHq;
  float s = 0.f;
#pragma unroll 8
  for (int d = 0; d < 64; ++d) s += qrow[d] * kp[d];
  red[t] = s; __syncthreads();
  for (int off = 128; off > 0; off >>= 1) {
    if (t < off) red[t] = fmaxf(red[t], red[t + off]);
    __syncthreads();
  }
  float mx = red[0]; __syncthreads();
  float p = __expf(s - mx);
  red[t] = p; __syncthreads();
  for (int off = 128; off > 0; off >>= 1) {
    if (t < off) red[t] += red[t + off];
    __syncthreads();
  }
  float inv = 1.0f / red[0];
  a2[((size_t)bh * Mq + i) * Mq + t] = p * inv;
}

// ---------------- scalars for pinv init ----------------
__global__ void k_zero2(float* sc) { if (threadIdx.x < 2) sc[threadIdx.x] = 0.0f; }

__global__ __launch_bounds__(256) void k_colrow(const float* __restrict__ a2,
                                                float* __restrict__ sc) {
  int bh = blockIdx.x, t = threadIdx.x;
  const float* a = a2 + (size_t)bh * Mq * Mq;
  float cs = 0.f, rs = 0.f;
  for (int i = 0; i < Mq; ++i) cs += fabsf(a[i * Mq + t]);  // column-sum
  for (int j = 0; j < Mq; ++j) rs += fabsf(a[t * Mq + j]);  // row-sum
  __shared__ float red[256];
  red[t] = rs; __syncthreads();
  for (int off = 128; off > 0; off >>= 1) {
    if (t < off) red[t] = fmaxf(red[t], red[t + off]);
    __syncthreads();
  }
  if (t == 0) atomicMax((unsigned int*)&sc[0], __float_as_uint(red[0]));
  __syncthreads();
  red[t] = cs; __syncthreads();
  for (int off = 128; off > 0; off >>= 1) {
    if (t < off) red[t] = fmaxf(red[t], red[t + off]);
    __syncthreads();
  }
  if (t == 0) atomicMax((unsigned int*)&sc[1], __float_as_uint(red[0]));
}

__global__ void k_zinit(const float* __restrict__ a2, const float* __restrict__ sc,
                        float* __restrict__ z) {
  size_t idx = (size_t)blockIdx.x * 256 + threadIdx.x;
  int bh = (int)(idx >> 16);
  int rem = (int)(idx & 65535);
  int i = rem >> 8, j = rem & 255;
  float inv = 1.0f / (sc[0] * sc[1]);
  z[idx] = a2[((size_t)bh << 16) + (j << 8) + i] * inv;
}

// ---------------- batched GEMM: C = scale * (A @ B'), B' = transform? aI-B : B ----
__global__ __launch_bounds__(256) void k_gemm_b(
    const float* __restrict__ A, const float* __restrict__ Bm, float* __restrict__ C,
    int Md, int Nd, int Kd, int transform, float alpha, float scale) {
  int bz = blockIdx.z;
  A += (size_t)bz * Md * Kd; Bm += (size_t)bz * Kd * Nd; C += (size_t)bz * Md * Nd;
  int n0 = blockIdx.x * 64, m0 = blockIdx.y * 64;
  __shared__ float As[16][64];
  __shared__ float Bs[16][64];
  int t = threadIdx.x, tx = t & 15, ty = t >> 4;
  float acc[4][4] = {};
  for (int k0 = 0; k0 < Kd; k0 += 16) {
    {
      int row = t >> 2, c4 = (t & 3) * 4;
      float4 av = *(const float4*)&A[(size_t)(m0 + row) * Kd + k0 + c4];
      As[c4 + 0][row] = av.x; As[c4 + 1][row] = av.y;
      As[c4 + 2][row] = av.z; As[c4 + 3][row] = av.w;
    }
    {
      int row = t >> 4, c4 = (t & 15) * 4;
      float4 bv = *(const float4*)&Bm[(size_t)(k0 + row) * Nd + n0 + c4];
      if (transform) {
        int kk = k0 + row, cc = n0 + c4;
        bv.x = ((kk == cc + 0) ? alpha : 0.0f) - bv.x;
        bv.y = ((kk == cc + 1) ? alpha : 0.0f) - bv.y;
        bv.z = ((kk == cc + 2) ? alpha : 0.0f) - bv.z;
        bv.w = ((kk == cc + 3) ? alpha : 0.0f) - bv.w;
      }
      *(float4*)&Bs[row][c4] = bv;
    }
    __syncthreads();
#pragma unroll
    for (int kk = 0; kk < 16; ++kk) {
      float4 a4 = *(const float4*)&As[kk][ty * 4];
      float4 b4 = *(const float4*)&Bs[kk][tx * 4];
      fma4x4(a4, b4, acc);
    }
    __syncthreads();
  }
#pragma unroll
  for (int i = 0; i < 4; ++i) {
    float4 val = make_float4(acc[i][0] * scale, acc[i][1] * scale,
                             acc[i][2] * scale, acc[i][3] * scale);
    *(float4*)&C[(size_t)(m0 + ty * 4 + i) * Nd + n0 + tx * 4] = val;
  }
}

// ---------------- flash attention: O = softmax(Q K^T) V  (dh=64) ----------------
// One block: 64 q-rows of one bh; KV tiled by 64 with online softmax.
__global__ __launch_bounds__(256) void k_flash(
    const float* __restrict__ Qg, const float* __restrict__ Kg,
    const float* __restrict__ Vg, float* __restrict__ Og, int nq, int nkv) {
  int bh = blockIdx.y, q0 = blockIdx.x * 64;
  Qg += (size_t)bh * nq * DHq;  Og += (size_t)bh * nq * DHq;
  Kg += (size_t)bh * nkv * DHq; Vg += (size_t)bh * nkv * DHq;
  __shared__ float qT[64][64];   // [kk][r]
  __shared__ float kps[64][64];  // K^T [kk][j], then reused as P [j][r]
  __shared__ float Vs[64][64];   // [j][d]
  int t = threadIdx.x, tx = t & 15, ty = t >> 4;
  int lrow = t >> 2, lcb = (t & 3) * 16;
#pragma unroll
  for (int o = 0; o < 4; ++o) {
    float4 qv = *(const float4*)&Qg[(size_t)(q0 + lrow) * DHq + lcb + o * 4];
    qT[lcb + o * 4 + 0][lrow] = qv.x; qT[lcb + o * 4 + 1][lrow] = qv.y;
    qT[lcb + o * 4 + 2][lrow] = qv.z; qT[lcb + o * 4 + 3][lrow] = qv.w;
  }
  float accO[4][4] = {};
  float mrun[4], lrun[4];
#pragma unroll
  for (int i = 0; i < 4; ++i) { mrun[i] = -3.0e38f; lrun[i] = 0.f; }
  for (int kv0 = 0; kv0 < nkv; kv0 += 64) {
    __syncthreads();  // prev tile fully consumed (also covers qT staging)
#pragma unroll
    for (int o = 0; o < 4; ++o) {
      float4 kv_ = *(const float4*)&Kg[(size_t)(kv0 + lrow) * DHq + lcb + o * 4];
      kps[lcb + o * 4 + 0][lrow] = kv_.x; kps[lcb + o * 4 + 1][lrow] = kv_.y;
      kps[lcb + o * 4 + 2][lrow] = kv_.z; kps[lcb + o * 4 + 3][lrow] = kv_.w;
      float4 vv = *(const float4*)&Vg[(size_t)(kv0 + lrow) * DHq + lcb + o * 4];
      *(float4*)&Vs[lrow][lcb + o * 4] = vv;
    }
    __syncthreads();
    float s[4][4] = {};
#pragma unroll 8
    for (int kk = 0; kk < 64; ++kk) {
      float4 a4 = *(const float4*)&qT[kk][ty * 4];
      float4 b4 = *(const float4*)&kps[kk][tx * 4];
      fma4x4(a4, b4, s);
    }
    __syncthreads();  // all waves done reading kps before P overwrite
#pragma unroll
    for (int i = 0; i < 4; ++i) {
      float mt = fmaxf(fmaxf(s[i][0], s[i][1]), fmaxf(s[i][2], s[i][3]));
      for (int off = 1; off < 16; off <<= 1) mt = fmaxf(mt, __shfl_xor(mt, off));
      float mnew = fmaxf(mrun[i], mt);
      float al = __expf(mrun[i] - mnew);
      float ps = 0.f;
#pragma unroll
      for (int j = 0; j < 4; ++j) { float p = __expf(s[i][j] - mnew); s[i][j] = p; ps += p; }
      for (int off = 1; off < 16; off <<= 1) ps += __shfl_xor(ps, off);
      lrun[i] = lrun[i] * al + ps;
      mrun[i] = mnew;
#pragma unroll
      for (int j = 0; j < 4; ++j) {
        accO[i][j] *= al;
        kps[tx * 4 + j][ty * 4 + i] = s[i][j];  // P[j_kv][r]
      }
    }
    __syncthreads();  // P visible
#pragma unroll 8
    for (int kk = 0; kk < 64; ++kk) {
      float4 p4 = *(const float4*)&kps[kk][ty * 4];
      float4 v4 = *(const float4*)&Vs[kk][tx * 4];
      fma4x4(p4, v4, accO);
    }
  }
#pragma unroll
  for (int i = 0; i < 4; ++i) {
    float inv = 1.0f / lrun[i];
    float4 val = make_float4(accO[i][0] * inv, accO[i][1] * inv,
                             accO[i][2] * inv, accO[i][3] * inv);
    *(float4*)&Og[(size_t)(q0 + ty * 4 + i) * DHq + tx * 4] = val;
  }
}

// ---------------- depthwise conv residual (33 taps along n), add in place ------
__global__ __launch_bounds__(256) void k_conv_add(const float* __restrict__ v,
                                                  const float* __restrict__ kern,
                                                  float* __restrict__ outh) {
  int bx = blockIdx.x;  // BH*N/4 blocks
  int bh = bx >> 10;
  int i0 = (bx & 1023) * 4;
  int t = threadIdx.x;
  int rr = t >> 6, d = t & 63;
  int h = bh & 7;
  int i = i0 + rr;
  const float* kc = kern + h * 33;
  float acc = 0.f;
#pragma unroll
  for (int u = 0; u < 33; ++u) {
    int row = i + u - 16;
    if (row >= 0 && row < Nq)
      acc += kc[u] * v[((size_t)bh * Nq + row) * DHq + d];
  }
  outh[((size_t)bh * Nq + i) * DHq + d] += acc;
}

// ---------------- final GEMM: out = gather(out_h) @ Wout + bias ----------------
__global__ __launch_bounds__(256) void k_gemm_final(
    const float* __restrict__ outh, const float* __restrict__ Wout,
    const float* __restrict__ bias, float* __restrict__ out) {
  int n0 = blockIdx.x * 64, m0 = blockIdx.y * 64;
  __shared__ float As[16][64];
  __shared__ float Bs[16][64];
  int t = threadIdx.x, tx = t & 15, ty = t >> 4;
  float acc[4][4] = {};
  for (int k0 = 0; k0 < INNERq; k0 += 16) {
    {
      int row = t >> 2, c4 = (t & 3) * 4;
      int grow = m0 + row, b = grow >> 12, ii = grow & 4095;
      int kk = k0 + c4, h = kk >> 6, d = kk & 63;
      float4 av = *(const float4*)&outh[((size_t)(b * Hq + h) * Nq + ii) * DHq + d];
      As[c4 + 0][row] = av.x; As[c4 + 1][row] = av.y;
      As[c4 + 2][row] = av.z; As[c4 + 3][row] = av.w;
    }
    {
      int row = t >> 4, c4 = (t & 15) * 4;
      float4 bv = *(const float4*)&Wout[(size_t)(k0 + row) * DIMq + n0 + c4];
      *(float4*)&Bs[row][c4] = bv;
    }
    __syncthreads();
#pragma unroll
    for (int kk = 0; kk < 16; ++kk) {
      float4 a4 = *(const float4*)&As[kk][ty * 4];
      float4 b4 = *(const float4*)&Bs[kk][tx * 4];
      fma4x4(a4, b4, acc);
    }
    __syncthreads();
  }
  int c = n0 + tx * 4;
  float4 bb = *(const float4*)&bias[c];
#pragma unroll
  for (int i = 0; i < 4; ++i) {
    int row = m0 + ty * 4 + i;
    float4 val = make_float4(acc[i][0] + bb.x, acc[i][1] + bb.y,
                             acc[i][2] + bb.z, acc[i][3] + bb.w);
    *(float4*)&out[(size_t)row * DIMq + c] = val;
  }
}

// ---------------- host ----------------
extern "C" void kernel_launch(void* const* d_in, const int* in_sizes, int n_in,
                              void* d_out, int out_size, void* d_ws, size_t ws_size,
                              hipStream_t stream) {
  const float* x      = (const float*)d_in[0];
  const float* w_qkv  = (const float*)d_in[1];
  const float* w_out  = (const float*)d_in[2];
  const float* b_out  = (const float*)d_in[3];
  const float* res_k  = (const float*)d_in[4];
  float* out = (float*)d_out;
  float* ws  = (float*)d_ws;

  float* q   = ws + O_Q;
  float* k   = ws + O_K;
  float* v   = ws + O_V;
  float* ql  = ws + O_QL;
  float* kl  = ws + O_KL;
  float* a2  = ws + O_A2;
  float* za  = ws + O_ZA;
  float* zb  = ws + O_ZB;
  float* xz  = ws + O_XZ;
  float* t1  = ws + O_T1;
  float* t2b = ws + O_T2;
  float* a3v = ws + O_A3V;
  float* Wm  = ws + O_W;
  float* oh  = ws + O_OH;
  float* sc  = ws + O_SC;

  // 1. qkv projection -> q,k,v in [bh][n][dh] (q scaled)
  k_gemm_qkv<<<dim3(24, 256), 256, 0, stream>>>(x, w_qkv, q, k, v);
  // 2. landmarks
  k_landmarks<<<dim3(BHq * Mq), 64, 0, stream>>>(q, k, ql, kl);
  // 3. attn2 softmax
  k_attn2<<<dim3(Mq, BHq), 256, 0, stream>>>(ql, kl, a2);
  // 4-5. global col/row maxima
  k_zero2<<<1, 64, 0, stream>>>(sc);
  k_colrow<<<dim3(BHq), 256, 0, stream>>>(a2, sc);
  // 6. z0 = a2^T / (col*row)
  k_zinit<<<dim3(BHq * Mq * Mq / 256), 256, 0, stream>>>(a2, sc, za);
  // 7. Newton-Schulz pinv iterations
  float* zc = za;
  float* zn = zb;
  for (int it = 0; it < 6; ++it) {
    k_gemm_b<<<dim3(4, 4, BHq), 256, 0, stream>>>(a2, zc, xz, Mq, Mq, Mq, 0, 0.f, 1.f);
    k_gemm_b<<<dim3(4, 4, BHq), 256, 0, stream>>>(xz, xz, t1, Mq, Mq, Mq, 1, 7.f, 1.f);
    k_gemm_b<<<dim3(4, 4, BHq), 256, 0, stream>>>(xz, t1, t2b, Mq, Mq, Mq, 1, 15.f, 1.f);
    k_gemm_b<<<dim3(4, 4, BHq), 256, 0, stream>>>(zc, t2b, zn, Mq, Mq, Mq, 1, 13.f, 0.25f);
    float* tmp = zc; zc = zn; zn = tmp;
  }
  // 8. attn3v = softmax(q_l k^T) v   [bh][m][dh]
  k_flash<<<dim3(Mq / 64, BHq), 256, 0, stream>>>(ql, k, v, a3v, Mq, Nq);
  // 9. W = pinv @ attn3v
  k_gemm_b<<<dim3(1, 4, BHq), 256, 0, stream>>>(zc, a3v, Wm, Mq, DHq, Mq, 0, 0.f, 1.f);
  // 10. out_h = softmax(q k_l^T) W
  k_flash<<<dim3(Nq / 64, BHq), 256, 0, stream>>>(q, kl, Wm, oh, Nq, Mq);
  // 11. += depthwise conv residual
  k_conv_add<<<dim3(BHq * Nq / 4), 256, 0, stream>>>(v, res_k, oh);
  // 12. final projection + bias
  k_gemm_final<<<dim3(8, 256), 256, 0, stream>>>(oh, w_out, b_out, out);
}

// Round 2
// 866.644 us; speedup vs baseline: 2.0882x; 2.0882x over previous
//
#include <hip/hip_runtime.h>

// ---------------- problem constants ----------------
#define Nq   4096
#define DHq  64
#define Mq   256
#define BHq  32

using bf16 = __bf16;
using bf16x8 = __bf16 __attribute__((ext_vector_type(8)));
using f32x4 = float __attribute__((ext_vector_type(4)));

__device__ __forceinline__ f32x4 mfma16(bf16x8 a, bf16x8 b, f32x4 c) {
  return __builtin_amdgcn_mfma_f32_16x16x32_bf16(a, b, c, 0, 0, 0);
}
__device__ __forceinline__ unsigned short f2bu(float f) {
  bf16 b = (bf16)f;
  return __builtin_bit_cast(unsigned short, b);
}

// Stage a ROWS x 32 bf16 tile into LDS, row stride 40 bf16 (80 B, 16B-aligned).
// SRC: 0 = bf16 row-major, 1 = f32 row-major, 2 = f32 gather from oh[bh][4096][64]
template<int ROWS, int SRC>
__device__ __forceinline__ void stageA(const void* src, long ld, long row0, int k0,
                                       bf16* dst, int t) {
#pragma unroll
  for (int c = 0; c < ROWS / 64; ++c) {
    int idx = t + 256 * c;
    int r = idx >> 2;
    int kc = (idx & 3) << 3;
    bf16x8 val;
    if constexpr (SRC == 0) {
      val = *(const bf16x8*)((const bf16*)src + (row0 + r) * ld + k0 + kc);
    } else if constexpr (SRC == 1) {
      const float* s = (const float*)src + (row0 + r) * ld + k0 + kc;
      float4 a = *(const float4*)s;
      float4 b = *(const float4*)(s + 4);
      val[0]=(bf16)a.x; val[1]=(bf16)a.y; val[2]=(bf16)a.z; val[3]=(bf16)a.w;
      val[4]=(bf16)b.x; val[5]=(bf16)b.y; val[6]=(bf16)b.z; val[7]=(bf16)b.w;
    } else {
      long m = row0 + r;
      long bb = m >> 12, ii = m & 4095;
      int k = k0 + kc;
      long h = k >> 6, d = k & 63;
      const float* s = (const float*)src + (((bb * 8 + h) * 4096 + ii) * 64 + d);
      float4 a = *(const float4*)s;
      float4 b = *(const float4*)(s + 4);
      val[0]=(bf16)a.x; val[1]=(bf16)a.y; val[2]=(bf16)a.z; val[3]=(bf16)a.w;
      val[4]=(bf16)b.x; val[5]=(bf16)b.y; val[6]=(bf16)b.z; val[7]=(bf16)b.w;
    }
    *(bf16x8*)(dst + r * 40 + kc) = val;
  }
}

// Stage 32 x COLS tile of row-major [K][N] B into word-LDS [COLS][20 words]
// (word kp = bf16 pair {k=2kp, k=2kp+1}); 16B-aligned rows (80 B stride).
template<int COLS, bool F32>
__device__ __forceinline__ void stageBN(const void* src, long ld, long n0, int k0,
                                        unsigned int* dst, int t) {
  int kp = t >> 4;
  int nb = (t & 15) << 2;
#pragma unroll
  for (int g = 0; g < COLS / 64; ++g) {
    int n = nb + (g << 6);
    unsigned int w0, w1, w2, w3;
    if constexpr (F32) {
      const float* s0 = (const float*)src + (long)(k0 + 2 * kp) * ld + n0 + n;
      const float* s1 = s0 + ld;
      float4 a = *(const float4*)s0;
      float4 b = *(const float4*)s1;
      w0 = f2bu(a.x) | ((unsigned)f2bu(b.x) << 16);
      w1 = f2bu(a.y) | ((unsigned)f2bu(b.y) << 16);
      w2 = f2bu(a.z) | ((unsigned)f2bu(b.z) << 16);
      w3 = f2bu(a.w) | ((unsigned)f2bu(b.w) << 16);
    } else {
      const unsigned short* s0 = (const unsigned short*)src + (long)(k0 + 2 * kp) * ld + n0 + n;
      const unsigned short* s1 = s0 + ld;
      ushort4 a = *(const ushort4*)s0;
      ushort4 b = *(const ushort4*)s1;
      w0 = a.x | ((unsigned)b.x << 16);
      w1 = a.y | ((unsigned)b.y << 16);
      w2 = a.z | ((unsigned)b.z << 16);
      w3 = a.w | ((unsigned)b.w << 16);
    }
    dst[(n + 0) * 20 + kp] = w0;
    dst[(n + 1) * 20 + kp] = w1;
    dst[(n + 2) * 20 + kp] = w2;
    dst[(n + 3) * 20 + kp] = w3;
  }
}

#define EQKV 0
#define EA2 1
#define EATOM 2
#define EROWDIV 3
#define EY 4
#define EG2 5
#define EG3 6
#define EG4 7
#define EWT 8
#define EBIAS 9

struct GP {
  const void* A; const void* Al;
  const void* B; const void* Bl;
  long ldA, ldB, sA, sB;
  int K;
  void* C0; void* C1; void* C2;
  long sC, ldC;
  const void* x0; const void* x1;
  const float* rs; float* rsw;
  const float* bias;
};

__device__ __forceinline__ void split_store(bf16* h, bf16* l, long idx, float v) {
  bf16 hi = (bf16)v;
  h[idx] = hi;
  l[idx] = (bf16)(v - (float)hi);
}

template<int BM, int BN, int WX, int ASRC, int BMODE, int SPLIT, int EPI>
__global__ __launch_bounds__(256, 2) void mgemm(GP p) {
  constexpr int WY = 4 / WX;
  constexpr int TM = BM / WY, TN = BN / WX;
  constexpr int IT = TM / 16, JT = TN / 16;
  __shared__ __align__(16) bf16 AsL[(SPLIT ? 2 : 1) * BM * 40];
  __shared__ __align__(16) unsigned int BsL[(SPLIT ? 2 : 1) * BN * 20];
  int t = threadIdx.x;
  int wv = t >> 6, lane = t & 63;
  int wy = wv / WX, wx = wv % WX;
  int qd = lane >> 4, lm = lane & 15;
  long bz = blockIdx.z;
  long m0 = (long)blockIdx.y * BM, n0 = (long)blockIdx.x * BN;

  const void* Ap; const void* Alp = nullptr;
  if constexpr (ASRC == 0) Ap = (const bf16*)p.A + bz * p.sA;
  else Ap = (const float*)p.A;
  if constexpr (SPLIT) Alp = (const bf16*)p.Al + bz * p.sA;
  const void* Bp; const void* Blp = nullptr;
  if constexpr (BMODE == 2) Bp = (const float*)p.B;
  else Bp = (const bf16*)p.B + bz * p.sB;
  if constexpr (SPLIT) Blp = (const bf16*)p.Bl + bz * p.sB;

  f32x4 acc[IT][JT];
#pragma unroll
  for (int i = 0; i < IT; ++i)
#pragma unroll
    for (int j = 0; j < JT; ++j) acc[i][j] = (f32x4)0.0f;

  for (int k0 = 0; k0 < p.K; k0 += 32) {
    stageA<BM, ASRC>(Ap, p.ldA, m0, k0, AsL, t);
    if constexpr (SPLIT) stageA<BM, 0>(Alp, p.ldA, m0, k0, AsL + BM * 40, t);
    if constexpr (BMODE == 0) {
      stageA<BN, 0>(Bp, p.ldB, n0, k0, (bf16*)BsL, t);
      if constexpr (SPLIT) stageA<BN, 0>(Blp, p.ldB, n0, k0, (bf16*)BsL + BN * 40, t);
    } else {
      stageBN<BN, BMODE == 2>(Bp, p.ldB, n0, k0, BsL, t);
      if constexpr (SPLIT) stageBN<BN, false>(Blp, p.ldB, n0, k0, BsL + BN * 20, t);
    }
    __syncthreads();
    bf16x8 af[IT], afl[IT];
#pragma unroll
    for (int i = 0; i < IT; ++i) {
      int m = wy * TM + i * 16 + lm;
      af[i] = *(const bf16x8*)(AsL + m * 40 + qd * 8);
      if constexpr (SPLIT) afl[i] = *(const bf16x8*)(AsL + BM * 40 + m * 40 + qd * 8);
    }
#pragma unroll
    for (int j = 0; j < JT; ++j) {
      int n = wx * TN + j * 16 + lm;
      bf16x8 bf, bfl;
      if constexpr (BMODE == 0) {
        bf = *(const bf16x8*)((const bf16*)BsL + n * 40 + qd * 8);
        if constexpr (SPLIT) bfl = *(const bf16x8*)((const bf16*)BsL + BN * 40 + n * 40 + qd * 8);
      } else {
        bf = *(const bf16x8*)((const bf16*)(BsL + n * 20 + qd * 4));
        if constexpr (SPLIT) bfl = *(const bf16x8*)((const bf16*)(BsL + BN * 20 + n * 20 + qd * 4));
      }
#pragma unroll
      for (int i = 0; i < IT; ++i) {
        acc[i][j] = mfma16(af[i], bf, acc[i][j]);
        if constexpr (SPLIT) {
          acc[i][j] = mfma16(af[i], bfl, acc[i][j]);
          acc[i][j] = mfma16(afl[i], bf, acc[i][j]);
        }
      }
    }
    __syncthreads();
  }

  // ---------------- epilogues ----------------
  if constexpr (EPI == EA2 || EPI == EATOM) {
#pragma unroll
    for (int r = 0; r < 4; ++r) {
      long row = m0 + wy * TM + qd * 4 + r;
      float e[JT];
      float s = 0.f;
#pragma unroll
      for (int j = 0; j < JT; ++j) { e[j] = __expf(acc[0][j][r]); s += e[j]; }
      s += __shfl_xor(s, 1); s += __shfl_xor(s, 2);
      s += __shfl_xor(s, 4); s += __shfl_xor(s, 8);
      if constexpr (EPI == EA2) {
        float inv = 1.0f / s;
#pragma unroll
        for (int j = 0; j < JT; ++j) {
          long col = n0 + j * 16 + lm;
          split_store((bf16*)p.C0, (bf16*)p.C1, bz * p.sC + row * p.ldC + col, e[j] * inv);
        }
      } else {
        if (lm == 0) atomicAdd(&p.rsw[bz * 256 + row], s);
#pragma unroll
        for (int j = 0; j < JT; ++j) {
          long col = n0 + j * 16 + lm;
          ((bf16*)p.C0)[bz * p.sC + row * p.ldC + col] = (bf16)e[j];
        }
      }
    }
  } else {
#pragma unroll
    for (int i = 0; i < IT; ++i)
#pragma unroll
      for (int j = 0; j < JT; ++j)
#pragma unroll
        for (int r = 0; r < 4; ++r) {
          long row = m0 + wy * TM + i * 16 + qd * 4 + r;
          long col = n0 + wx * TN + j * 16 + lm;
          float v = acc[i][j][r];
          if constexpr (EPI == EQKV) {
            int part = (int)(col >> 9);
            long h = (col >> 6) & 7, d = col & 63;
            long bb = row >> 12, ii = row & 4095;
            float scv = part == 0 ? 0.125f : 1.0f;
            bf16* dst = part == 0 ? (bf16*)p.C0 : (part == 1 ? (bf16*)p.C1 : (bf16*)p.C2);
            dst[((bb * 8 + h) * 4096 + ii) * 64 + d] = (bf16)(v * scv);
          } else if constexpr (EPI == EROWDIV) {
            float pv = v / p.rs[bz * 256 + row];
            split_store((bf16*)p.C0, (bf16*)p.C1, bz * p.sC + row * p.ldC + col, pv);
          } else if constexpr (EPI == EY) {
            split_store((bf16*)p.C0, (bf16*)p.C1, bz * 65536 + row * 256 + col, v);
          } else if constexpr (EPI == EG2) {
            long ix = bz * 65536 + row * 256 + col;
            float y = (float)((const bf16*)p.x0)[ix] + (float)((const bf16*)p.x1)[ix];
            float val = (row == col ? 15.0f : 0.0f) - 7.0f * y + v;
            split_store((bf16*)p.C0, (bf16*)p.C1, ix, val);
          } else if constexpr (EPI == EG3) {
            float val = (row == col ? 13.0f : 0.0f) - v;
            split_store((bf16*)p.C0, (bf16*)p.C1, bz * 65536 + row * 256 + col, val);
          } else if constexpr (EPI == EG4) {
            split_store((bf16*)p.C0, (bf16*)p.C1, bz * 65536 + row * 256 + col, 0.25f * v);
          } else if constexpr (EPI == EWT) {
            ((bf16*)p.C0)[bz * 16384 + col * 256 + row] = (bf16)v;
          } else if constexpr (EPI == EBIAS) {
            ((float*)p.C0)[row * 512 + col] = v + p.bias[col];
          }
        }
  }
}

// ---------------- small kernels ----------------
__global__ void k_zero(float* rs3, unsigned int* sc) {
  int i = blockIdx.x * 256 + threadIdx.x;
  if (i < 8192) rs3[i] = 0.f;
  if (i == 0) sc[0] = 0u;
}

__global__ void k_landmarks(const bf16* q, const bf16* k, bf16* qlh, bf16* qll,
                            bf16* klh, bf16* kll) {
  int bm = blockIdx.x;
  int bh = bm >> 8, mi = bm & 255;
  int d = threadIdx.x;
  const bf16* qp = q + ((long)bh * 4096 + mi * 16) * 64 + d;
  const bf16* kp = k + ((long)bh * 4096 + mi * 16) * 64 + d;
  float sq = 0.f, sk = 0.f;
#pragma unroll
  for (int tt = 0; tt < 16; ++tt) { sq += (float)qp[tt * 64]; sk += (float)kp[tt * 64]; }
  sq *= 0.0625f; sk *= 0.0625f;
  long o = (long)bh * 16384 + mi * 64 + d;
  split_store(qlh, qll, o, sq);
  split_store(klh, kll, o, sk);
}

__global__ __launch_bounds__(256) void k_colsum(const bf16* A2h, const bf16* A2l,
                                                unsigned int* sc) {
  int bh = blockIdx.x, j = threadIdx.x;
  const bf16* ph = A2h + (long)bh * 65536 + j;
  const bf16* pl = A2l + (long)bh * 65536 + j;
  float s = 0.f;
  for (int i = 0; i < 256; ++i) s += (float)ph[i * 256] + (float)pl[i * 256];
  __shared__ float red[256];
  red[j] = s; __syncthreads();
  for (int o = 128; o > 0; o >>= 1) {
    if (j < o) red[j] = fmaxf(red[j], red[j + o]);
    __syncthreads();
  }
  if (j == 0) atomicMax(sc, __float_as_uint(red[0]));
}

__global__ __launch_bounds__(256) void k_zinit(const bf16* A2h, const bf16* A2l,
                                               const unsigned int* sc, bf16* zh, bf16* zl) {
  __shared__ float T[64][65];
  int bh = blockIdx.z, ti = blockIdx.y, tj = blockIdx.x;
  int t = threadIdx.x;
  int c = t & 63, r0 = t >> 6;
  long base = (long)bh * 65536;
  float inv = 1.0f / __uint_as_float(sc[0]);
#pragma unroll
  for (int rr = 0; rr < 16; ++rr) {
    int r = r0 * 16 + rr;
    long idx = base + (long)(ti * 64 + r) * 256 + tj * 64 + c;
    T[r][c] = (float)A2h[idx] + (float)A2l[idx];
  }
  __syncthreads();
#pragma unroll
  for (int rr = 0; rr < 16; ++rr) {
    int jl = r0 * 16 + rr;
    float v = T[c][jl] * inv;
    long o = base + (long)(tj * 64 + jl) * 256 + ti * 64 + c;
    split_store(zh, zl, o, v);
  }
}

__global__ __launch_bounds__(256) void k_conv(const bf16* v, const float* kern, float* oh) {
  int bx = blockIdx.x;
  int bh = bx >> 10, i0 = (bx & 1023) * 4;
  int t = threadIdx.x, rr = t >> 6, d = t & 63;
  int h = bh & 7, i = i0 + rr;
  const float* kc = kern + h * 33;
  float acc = 0.f;
#pragma unroll
  for (int u = 0; u < 33; ++u) {
    int row = i + u - 16;
    if (row >= 0 && row < 4096) acc += kc[u] * (float)v[((long)bh * 4096 + row) * 64 + d];
  }
  oh[((long)bh * 4096 + i) * 64 + d] += acc;
}

// fused: oh = softmax(q @ kl^T) @ W, per 64-row tile; W given transposed (Wt [bh][64][256])
__global__ __launch_bounds__(256, 2) void k_attn1w(const bf16* qb, const bf16* klb,
                                                   const bf16* Wt, float* oh) {
  __shared__ __align__(16) char L[38912];
  bf16* Aq = (bf16*)L;             // [64][40]
  bf16* Bkl = (bf16*)(L + 5120);   // [256][40]
  bf16* Pl = (bf16*)L;             // [64][264] (reuse after stage-1)
  bf16* Bw = (bf16*)(L + 33792);   // [64][40]
  int t = threadIdx.x, wv = t >> 6, lane = t & 63;
  int qd = lane >> 4, lm = lane & 15;
  long bz = blockIdx.z;
  long m0 = (long)blockIdx.x * 64;
  const bf16* qA = qb + bz * (4096L * 64);
  const bf16* klA = klb + bz * (256L * 64);
  const bf16* WtA = Wt + bz * 16384;

  f32x4 a1[16];
#pragma unroll
  for (int j = 0; j < 16; ++j) a1[j] = (f32x4)0.0f;
  for (int k0 = 0; k0 < 64; k0 += 32) {
    stageA<64, 0>(qA, 64, m0, k0, Aq, t);
    stageA<256, 0>(klA, 64, 0, k0, Bkl, t);
    __syncthreads();
    bf16x8 af = *(const bf16x8*)(Aq + (wv * 16 + lm) * 40 + qd * 8);
#pragma unroll
    for (int j = 0; j < 16; ++j) {
      bf16x8 bf = *(const bf16x8*)(Bkl + (j * 16 + lm) * 40 + qd * 8);
      a1[j] = mfma16(af, bf, a1[j]);
    }
    __syncthreads();
  }
  float rs[4];
#pragma unroll
  for (int r = 0; r < 4; ++r) {
    int rowl = wv * 16 + qd * 4 + r;
    float ev[16];
    float s = 0.f;
#pragma unroll
    for (int j = 0; j < 16; ++j) { ev[j] = __expf(a1[j][r]); s += ev[j]; }
    s += __shfl_xor(s, 1); s += __shfl_xor(s, 2);
    s += __shfl_xor(s, 4); s += __shfl_xor(s, 8);
    rs[r] = s;
#pragma unroll
    for (int j = 0; j < 16; ++j) {
      float other = __shfl_xor(ev[j], 1);
      if ((lm & 1) == 0) {
        unsigned int w = f2bu(ev[j]) | ((unsigned)f2bu(other) << 16);
        *(unsigned int*)(Pl + rowl * 264 + j * 16 + lm) = w;
      }
    }
  }
  f32x4 a2[4];
#pragma unroll
  for (int j = 0; j < 4; ++j) a2[j] = (f32x4)0.0f;
  for (int k0 = 0; k0 < 256; k0 += 32) {
    stageA<64, 0>(WtA, 256, 0, k0, Bw, t);
    __syncthreads();
    bf16x8 af = *(const bf16x8*)(Pl + (wv * 16 + lm) * 264 + k0 + qd * 8);
#pragma unroll
    for (int j = 0; j < 4; ++j) {
      bf16x8 bf = *(const bf16x8*)(Bw + (j * 16 + lm) * 40 + qd * 8);
      a2[j] = mfma16(af, bf, a2[j]);
    }
    __syncthreads();
  }
#pragma unroll
  for (int j = 0; j < 4; ++j)
#pragma unroll
    for (int r = 0; r < 4; ++r) {
      long grow = m0 + wv * 16 + qd * 4 + r;
      long col = j * 16 + lm;
      oh[(bz * 4096 + grow) * 64 + col] = a2[j][r] / rs[r];
    }
}

// ---------------- host ----------------
extern "C" void kernel_launch(void* const* d_in, const int* in_sizes, int n_in,
                              void* d_out, int out_size, void* d_ws, size_t ws_size,
                              hipStream_t stream) {
  const float* x     = (const float*)d_in[0];
  const float* w_qkv = (const float*)d_in[1];
  const float* w_out = (const float*)d_in[2];
  const float* b_out = (const float*)d_in[3];
  const float* res_k = (const float*)d_in[4];

  char* w = (char*)d_ws;
  bf16* qb  = (bf16*)(w);
  bf16* kb  = (bf16*)(w + 16777216);
  bf16* vb  = (bf16*)(w + 33554432);
  bf16* qlh = (bf16*)(w + 50331648);
  bf16* qll = (bf16*)(w + 51380224);
  bf16* klh = (bf16*)(w + 52428800);
  bf16* kll = (bf16*)(w + 53477376);
  bf16* A2h = (bf16*)(w + 54525952);
  bf16* A2l = (bf16*)(w + 58720256);
  bf16* zAh = (bf16*)(w + 62914560);
  bf16* zAl = (bf16*)(w + 67108864);
  bf16* zBh = (bf16*)(w + 71303168);
  bf16* zBl = (bf16*)(w + 75497472);
  char* R   = w + 79691776;           // 64 MiB region: P3b, later pinv temps + oh
  bf16* P3b = (bf16*)R;
  bf16* yh  = (bf16*)(R);
  bf16* yl  = (bf16*)(R + 4194304);
  bf16* bbh = (bf16*)(R + 8388608);
  bf16* bbl = (bf16*)(R + 12582912);
  bf16* cch = (bf16*)(R + 16777216);
  bf16* ccl = (bf16*)(R + 20971520);
  float* oh = (float*)(R + 25165824);
  float* rs3 = (float*)(w + 146800640);
  unsigned int* sc = (unsigned int*)(w + 146833408);
  bf16* a3vh = (bf16*)(w + 146833664);
  bf16* a3vl = (bf16*)(w + 147882240);
  bf16* Wt   = (bf16*)(w + 148930560);

  GP p;

  k_zero<<<33, 256, 0, stream>>>(rs3, sc);

  // qkv projection (fp32 in, bf16 head-layout out, q scaled)
  p = GP{};
  p.A = x; p.ldA = 512; p.B = w_qkv; p.ldB = 1536; p.K = 512;
  p.C0 = qb; p.C1 = kb; p.C2 = vb;
  mgemm<128, 128, 2, 1, 2, 0, EQKV><<<dim3(12, 128, 1), 256, 0, stream>>>(p);

  k_landmarks<<<8192, 64, 0, stream>>>(qb, kb, qlh, qll, klh, kll);

  // attn2 = softmax(ql @ kl^T), split-precision, normalized in-block
  p = GP{};
  p.A = qlh; p.Al = qll; p.ldA = 64; p.sA = 16384;
  p.B = klh; p.Bl = kll; p.ldB = 64; p.sB = 16384; p.K = 64;
  p.C0 = A2h; p.C1 = A2l; p.sC = 65536; p.ldC = 256;
  mgemm<64, 256, 1, 0, 0, 1, EA2><<<dim3(1, 4, 32), 256, 0, stream>>>(p);

  k_colsum<<<32, 256, 0, stream>>>(A2h, A2l, sc);
  k_zinit<<<dim3(4, 4, 32), 256, 0, stream>>>(A2h, A2l, sc, zAh, zAl);

  // P3 = exp(ql @ k^T) unnormalized + row sums
  p = GP{};
  p.A = qlh; p.ldA = 64; p.sA = 16384;
  p.B = kb; p.ldB = 64; p.sB = 262144; p.K = 64;
  p.C0 = P3b; p.sC = 1048576; p.ldC = 4096; p.rsw = rs3;
  mgemm<64, 256, 1, 0, 0, 0, EATOM><<<dim3(16, 4, 32), 256, 0, stream>>>(p);

  // a3v = (P3 @ v) / rs3 -> split
  p = GP{};
  p.A = P3b; p.ldA = 4096; p.sA = 1048576;
  p.B = vb; p.ldB = 64; p.sB = 262144; p.K = 4096;
  p.C0 = a3vh; p.C1 = a3vl; p.sC = 16384; p.ldC = 64; p.rs = rs3;
  mgemm<64, 64, 2, 0, 1, 0, EROWDIV><<<dim3(1, 4, 32), 256, 0, stream>>>(p);

  // Newton-Schulz pinv, split-bf16
  bf16 *zch = zAh, *zcl = zAl, *znh = zBh, *znl = zBl;
  for (int it = 0; it < 6; ++it) {
    p = GP{};
    p.A = A2h; p.Al = A2l; p.ldA = 256; p.sA = 65536;
    p.B = zch; p.Bl = zcl; p.ldB = 256; p.sB = 65536; p.K = 256;
    p.C0 = yh; p.C1 = yl;
    mgemm<64, 64, 2, 0, 1, 1, EY><<<dim3(4, 4, 32), 256, 0, stream>>>(p);
    p.A = yh; p.Al = yl; p.B = yh; p.Bl = yl;
    p.C0 = bbh; p.C1 = bbl; p.x0 = yh; p.x1 = yl;
    mgemm<64, 64, 2, 0, 1, 1, EG2><<<dim3(4, 4, 32), 256, 0, stream>>>(p);
    p.A = yh; p.Al = yl; p.B = bbh; p.Bl = bbl; p.C0 = cch; p.C1 = ccl;
    mgemm<64, 64, 2, 0, 1, 1, EG3><<<dim3(4, 4, 32), 256, 0, stream>>>(p);
    p.A = zch; p.Al = zcl; p.B = cch; p.Bl = ccl; p.C0 = znh; p.C1 = znl;
    mgemm<64, 64, 2, 0, 1, 1, EG4><<<dim3(4, 4, 32), 256, 0, stream>>>(p);
    bf16* tmp;
    tmp = zch; zch = znh; znh = tmp;
    tmp = zcl; zcl = znl; znl = tmp;
  }

  // Wt = (z @ a3v)^T
  p = GP{};
  p.A = zch; p.Al = zcl; p.ldA = 256; p.sA = 65536;
  p.B = a3vh; p.Bl = a3vl; p.ldB = 64; p.sB = 16384; p.K = 256;
  p.C0 = Wt;
  mgemm<64, 64, 2, 0, 1, 1, EWT><<<dim3(1, 4, 32), 256, 0, stream>>>(p);

  // oh = softmax(q @ kl^T) @ W (fused)
  k_attn1w<<<dim3(64, 1, 32), 256, 0, stream>>>(qb, klh, Wt, oh);

  // += depthwise conv residual
  k_conv<<<32768, 256, 0, stream>>>(vb, res_k, oh);

  // out = gather(oh) @ w_out + bias
  p = GP{};
  p.A = oh; p.B = w_out; p.ldB = 512; p.K = 512;
  p.C0 = d_out; p.bias = b_out;
  mgemm<128, 128, 2, 2, 2, 0, EBIAS><<<dim3(4, 128, 1), 256, 0, stream>>>(p);
}